// Round 5
// baseline (346.871 us; speedup 1.0000x reference)
//
#include <hip/hip_runtime.h>
#include <math.h>

typedef __bf16 bf16x8 __attribute__((ext_vector_type(8)));
typedef float f32x4 __attribute__((ext_vector_type(4)));

// ---------------- weight conversion: fp32 -> bf16 frag-major in d_ws ----------
// Frag (kt,nt) = 32x16 block of B; lane L holds B[kt*32+(L>>4)*8+j][nt*16+(L&15)],
// j=0..7 -> one 16B chunk at frag*1024 + L*16. Frag ids: L1 0..47 (kt*16+nt),
// L2 48..111 (kt*8+nt), L3 112..127 (kt*4+nt), L4 128..143 (kt*8+nt, N pad 128).
__global__ void conv_weights(const float* __restrict__ W1, const float* __restrict__ W2,
                             const float* __restrict__ W3, const float* __restrict__ W4,
                             __bf16* __restrict__ ws)
{
  const int f = blockIdx.x * 4 + (threadIdx.x >> 6);
  const int lane = threadIdx.x & 63;
  int f0, ntot, Ksrc, Nsrc, off;
  const float* W;
  if (f < 48)       { f0 = f;       ntot = 16; Ksrc = 80;  Nsrc = 256; W = W1; off = 0; }
  else if (f < 112) { f0 = f - 48;  ntot = 8;  Ksrc = 256; Nsrc = 128; W = W2; off = 24576; }
  else if (f < 128) { f0 = f - 112; ntot = 4;  Ksrc = 128; Nsrc = 64;  W = W3; off = 57344; }
  else              { f0 = f - 128; ntot = 8;  Ksrc = 64;  Nsrc = 101; W = W4; off = 65536; }
  const int kt = f0 / ntot, nt = f0 % ntot;
  const int q = lane >> 4, c = lane & 15;
  const int n = nt * 16 + c;
  bf16x8 v;
#pragma unroll
  for (int j = 0; j < 8; ++j) {
    const int k = kt * 32 + q * 8 + j;
    const float x = (k < Ksrc && n < Nsrc) ? W[k * Nsrc + n] : 0.f;
    v[j] = (__bf16)x;
  }
  ((bf16x8*)(ws + off))[f0 * 64 + lane] = v;
}

// ---- stage nf frags (1 KB each) from ws[f0..] into LDS wbuf (coalesced 16B) --
__device__ __forceinline__ void stage_frags(const __bf16* __restrict__ ws,
                                            __bf16* __restrict__ wbuf,
                                            int f0, int nf, int t)
{
  const uint4* __restrict__ src = (const uint4*)(ws + (size_t)f0 * 512);
  uint4* __restrict__ dst = (uint4*)wbuf;
  const int cnt = nf * 64;
  for (int i = t; i < cnt; i += 256) dst[i] = src[i];
}

__device__ __forceinline__ bf16x8 wfrag(const __bf16* __restrict__ wbuf, int slot, int lane)
{
  return *(const bf16x8*)(wbuf + slot * 512 + lane * 8);
}

// ================= K12: x -> h1 (wave LDS) -> h2 (global, A-frag stream) ======
__global__ __launch_bounds__(256, 2)
void k12(const float* __restrict__ obs, const float* __restrict__ act,
         const float* __restrict__ b1, const float* __restrict__ g1, const float* __restrict__ be1,
         const float* __restrict__ b2, const float* __restrict__ g2, const float* __restrict__ be2,
         const __bf16* __restrict__ ws, __bf16* __restrict__ h2f)
{
  __shared__ __bf16 wbuf[16384];          // 32 KB weight staging
  __shared__ __bf16 h1s[4][16 * 264];     // per-wave h1 (also h2 transpose buf)
  const int t = threadIdx.x;
  const int wv = t >> 6, lane = t & 63;
  const int q = lane >> 4, c = lane & 15;
  const int tile = blockIdx.x * 4 + wv;   // 16-row tile id
  const int row0w = tile * 16;
  __bf16* h1 = &h1s[wv][0];

  // ---- A1 build from global (overlaps first staging)
  bf16x8 A1[3];
  {
    const float4* ob4 = (const float4*)(obs + (size_t)(row0w + c) * 60);
    const float4* ac4 = (const float4*)(act + (size_t)(row0w + c) * 20);
#pragma unroll
    for (int kt = 0; kt < 3; ++kt) {
      const int k0 = kt * 32 + q * 8;
      float v[8];
      if (k0 < 56) {
        const float4 a = ob4[k0 / 4], b = ob4[k0 / 4 + 1];
        v[0]=a.x; v[1]=a.y; v[2]=a.z; v[3]=a.w; v[4]=b.x; v[5]=b.y; v[6]=b.z; v[7]=b.w;
      } else if (k0 == 56) {
        const float4 a = ob4[14], b = ac4[0];
        v[0]=a.x; v[1]=a.y; v[2]=a.z; v[3]=a.w; v[4]=b.x; v[5]=b.y; v[6]=b.z; v[7]=b.w;
      } else if (k0 < 80) {
        const float4 a = ac4[(k0 - 60) / 4], b = ac4[(k0 - 60) / 4 + 1];
        v[0]=a.x; v[1]=a.y; v[2]=a.z; v[3]=a.w; v[4]=b.x; v[5]=b.y; v[6]=b.z; v[7]=b.w;
      } else {
#pragma unroll
        for (int j = 0; j < 8; ++j) v[j] = 0.f;
      }
#pragma unroll
      for (int j = 0; j < 8; ++j) A1[kt][j] = (__bf16)v[j];
    }
  }

  // ---- Layer 1: K chunks kt{0,1} then kt{2}
  f32x4 acc1[16];
#pragma unroll
  for (int nt = 0; nt < 16; ++nt) {
    const float bb = b1[nt * 16 + c];
    f32x4 vv = {bb, bb, bb, bb};
    acc1[nt] = vv;
  }
  stage_frags(ws, wbuf, 0, 32, t);
  __syncthreads();
#pragma unroll
  for (int kt = 0; kt < 2; ++kt)
#pragma unroll
    for (int nt = 0; nt < 16; ++nt)
      acc1[nt] = __builtin_amdgcn_mfma_f32_16x16x32_bf16(A1[kt], wfrag(wbuf, kt * 16 + nt, lane), acc1[nt], 0, 0, 0);
  __syncthreads();
  stage_frags(ws, wbuf, 32, 16, t);
  __syncthreads();
#pragma unroll
  for (int nt = 0; nt < 16; ++nt)
    acc1[nt] = __builtin_amdgcn_mfma_f32_16x16x32_bf16(A1[2], wfrag(wbuf, nt, lane), acc1[nt], 0, 0, 0);

  // ---- LN(256)+SiLU -> h1 (stride 264)
  {
    float mu[4], rs[4];
#pragma unroll
    for (int r = 0; r < 4; ++r) {
      float s = 0.f, s2 = 0.f;
#pragma unroll
      for (int nt = 0; nt < 16; ++nt) { const float v = acc1[nt][r]; s += v; s2 += v * v; }
      s += __shfl_xor(s, 1); s2 += __shfl_xor(s2, 1);
      s += __shfl_xor(s, 2); s2 += __shfl_xor(s2, 2);
      s += __shfl_xor(s, 4); s2 += __shfl_xor(s2, 4);
      s += __shfl_xor(s, 8); s2 += __shfl_xor(s2, 8);
      const float m = s * (1.f / 256.f);
      mu[r] = m;
      rs[r] = rsqrtf(s2 * (1.f / 256.f) - m * m + 1e-5f);
    }
#pragma unroll
    for (int nt = 0; nt < 16; ++nt) {
      const int col = nt * 16 + c;
      const float gg = g1[col], bb = be1[col];
#pragma unroll
      for (int r = 0; r < 4; ++r) {
        float v = (acc1[nt][r] - mu[r]) * rs[r] * gg + bb;
        v = v * __builtin_amdgcn_rcpf(1.f + __expf(-v));
        h1[(4 * q + r) * 264 + col] = (__bf16)v;
      }
    }
  }
  __syncthreads();

  // ---- Layer 2: K chunks kt{0..3}, kt{4..7}
  f32x4 acc2[8];
#pragma unroll
  for (int nt = 0; nt < 8; ++nt) {
    const float bb = b2[nt * 16 + c];
    f32x4 vv = {bb, bb, bb, bb};
    acc2[nt] = vv;
  }
  stage_frags(ws, wbuf, 48, 32, t);
  __syncthreads();
#pragma unroll
  for (int kt = 0; kt < 4; ++kt) {
    const bf16x8 A2 = *(const bf16x8*)(h1 + c * 264 + kt * 32 + q * 8);
#pragma unroll
    for (int nt = 0; nt < 8; ++nt)
      acc2[nt] = __builtin_amdgcn_mfma_f32_16x16x32_bf16(A2, wfrag(wbuf, kt * 8 + nt, lane), acc2[nt], 0, 0, 0);
  }
  __syncthreads();
  stage_frags(ws, wbuf, 80, 32, t);
  __syncthreads();
#pragma unroll
  for (int kt = 4; kt < 8; ++kt) {
    const bf16x8 A2 = *(const bf16x8*)(h1 + c * 264 + kt * 32 + q * 8);
#pragma unroll
    for (int nt = 0; nt < 8; ++nt)
      acc2[nt] = __builtin_amdgcn_mfma_f32_16x16x32_bf16(A2, wfrag(wbuf, (kt - 4) * 8 + nt, lane), acc2[nt], 0, 0, 0);
  }

  // ---- LN(128)+SiLU -> transpose buf (h1 region, stride 136) -> h2f stream
  {
    float mu[4], rs[4];
#pragma unroll
    for (int r = 0; r < 4; ++r) {
      float s = 0.f, s2 = 0.f;
#pragma unroll
      for (int nt = 0; nt < 8; ++nt) { const float v = acc2[nt][r]; s += v; s2 += v * v; }
      s += __shfl_xor(s, 1); s2 += __shfl_xor(s2, 1);
      s += __shfl_xor(s, 2); s2 += __shfl_xor(s2, 2);
      s += __shfl_xor(s, 4); s2 += __shfl_xor(s2, 4);
      s += __shfl_xor(s, 8); s2 += __shfl_xor(s2, 8);
      const float m = s * (1.f / 128.f);
      mu[r] = m;
      rs[r] = rsqrtf(s2 * (1.f / 128.f) - m * m + 1e-5f);
    }
    __bf16* hs = h1;  // reinterpret wave region as [16][136]
#pragma unroll
    for (int nt = 0; nt < 8; ++nt) {
      const int col = nt * 16 + c;
      const float gg = g2[col], bb = be2[col];
#pragma unroll
      for (int r = 0; r < 4; ++r) {
        float v = (acc2[nt][r] - mu[r]) * rs[r] * gg + bb;
        v = v * __builtin_amdgcn_rcpf(1.f + __expf(-v));
        hs[(4 * q + r) * 136 + col] = (__bf16)v;
      }
    }
    // read back as A-frags, store coalesced to global stream
#pragma unroll
    for (int kt = 0; kt < 4; ++kt) {
      const bf16x8 v = *(const bf16x8*)(hs + c * 136 + kt * 32 + q * 8);
      *(bf16x8*)(h2f + ((size_t)(tile * 4 + kt) * 64 + lane) * 8) = v;
    }
  }
}

// ================= K34: h2f -> L3 -> L4 -> softmax -> C51 projection ==========
__global__ __launch_bounds__(256, 2)
void k34(const float* __restrict__ rew, const float* __restrict__ boot,
         const float* __restrict__ disc, const float* __restrict__ qsup,
         const float* __restrict__ b3, const float* __restrict__ g3, const float* __restrict__ be3,
         const float* __restrict__ b4,
         const __bf16* __restrict__ ws, const __bf16* __restrict__ h2f,
         float* __restrict__ out)
{
  __shared__ __bf16 wbuf[16384];      // W3 slots 0..15, W4 slots 16..31
  __shared__ float pws[4][2192];      // per-wave: h3 (576 f32 as bf16[16][72]) + proj[16][101]
  const int t = threadIdx.x;
  const int wv = t >> 6, lane = t & 63;
  const int q = lane >> 4, c = lane & 15;
  __bf16* h3 = (__bf16*)&pws[wv][0];
  float* proj = &pws[wv][576];

  stage_frags(ws, wbuf, 112, 32, t);
  __syncthreads();

  for (int s = 0; s < 2; ++s) {
    const int tile = blockIdx.x * 8 + wv * 2 + s;
    const int row0w = tile * 16;

    // ---- A3 frags: coalesced stream loads
    bf16x8 A3[4];
#pragma unroll
    for (int kt = 0; kt < 4; ++kt)
      A3[kt] = *(const bf16x8*)(h2f + ((size_t)(tile * 4 + kt) * 64 + lane) * 8);

    // ---- Layer 3: 128 -> 64, LN+SiLU
    f32x4 acc3[4];
#pragma unroll
    for (int nt = 0; nt < 4; ++nt) {
      const float bb = b3[nt * 16 + c];
      f32x4 vv = {bb, bb, bb, bb};
      acc3[nt] = vv;
    }
#pragma unroll
    for (int kt = 0; kt < 4; ++kt)
#pragma unroll
      for (int nt = 0; nt < 4; ++nt)
        acc3[nt] = __builtin_amdgcn_mfma_f32_16x16x32_bf16(A3[kt], wfrag(wbuf, kt * 4 + nt, lane), acc3[nt], 0, 0, 0);
    {
      float mu[4], rs[4];
#pragma unroll
      for (int r = 0; r < 4; ++r) {
        float ss = 0.f, s2 = 0.f;
#pragma unroll
        for (int nt = 0; nt < 4; ++nt) { const float v = acc3[nt][r]; ss += v; s2 += v * v; }
        ss += __shfl_xor(ss, 1); s2 += __shfl_xor(s2, 1);
        ss += __shfl_xor(ss, 2); s2 += __shfl_xor(s2, 2);
        ss += __shfl_xor(ss, 4); s2 += __shfl_xor(s2, 4);
        ss += __shfl_xor(ss, 8); s2 += __shfl_xor(s2, 8);
        const float m = ss * (1.f / 64.f);
        mu[r] = m;
        rs[r] = rsqrtf(s2 * (1.f / 64.f) - m * m + 1e-5f);
      }
#pragma unroll
      for (int nt = 0; nt < 4; ++nt) {
        const int col = nt * 16 + c;
        const float gg = g3[col], bb = be3[col];
#pragma unroll
        for (int r = 0; r < 4; ++r) {
          float v = (acc3[nt][r] - mu[r]) * rs[r] * gg + bb;
          v = v * __builtin_amdgcn_rcpf(1.f + __expf(-v));
          h3[(4 * q + r) * 72 + col] = (__bf16)v;
        }
      }
    }

    // ---- Layer 4 + softmax + projection (wave-local)
    f32x4 a4[7];
#pragma unroll
    for (int nt = 0; nt < 7; ++nt) {
      const int col = nt * 16 + c;
      const float bb = (col < 101) ? b4[col] : 0.f;
      f32x4 vv = {bb, bb, bb, bb};
      a4[nt] = vv;
    }
#pragma unroll
    for (int kt = 0; kt < 2; ++kt) {
      const bf16x8 A4 = *(const bf16x8*)(h3 + c * 72 + kt * 32 + q * 8);
#pragma unroll
      for (int nt = 0; nt < 7; ++nt)
        a4[nt] = __builtin_amdgcn_mfma_f32_16x16x32_bf16(A4, wfrag(wbuf, 16 + kt * 8 + nt, lane), a4[nt], 0, 0, 0);
    }

    {
      f32x4 z = {0.f, 0.f, 0.f, 0.f};
      f32x4* p4 = (f32x4*)proj;
      for (int i = lane; i < 404; i += 64) p4[i] = z;
    }

    float mx4[4] = {-3.4e38f, -3.4e38f, -3.4e38f, -3.4e38f};
#pragma unroll
    for (int nt = 0; nt < 7; ++nt) {
      const bool ok = (nt < 6) | (c < 5);
#pragma unroll
      for (int r = 0; r < 4; ++r)
        if (ok) mx4[r] = fmaxf(mx4[r], a4[nt][r]);
    }
#pragma unroll
    for (int r = 0; r < 4; ++r) {
      mx4[r] = fmaxf(mx4[r], __shfl_xor(mx4[r], 1));
      mx4[r] = fmaxf(mx4[r], __shfl_xor(mx4[r], 2));
      mx4[r] = fmaxf(mx4[r], __shfl_xor(mx4[r], 4));
      mx4[r] = fmaxf(mx4[r], __shfl_xor(mx4[r], 8));
    }
    float sm4[4] = {0.f, 0.f, 0.f, 0.f};
#pragma unroll
    for (int nt = 0; nt < 7; ++nt) {
      const bool ok = (nt < 6) | (c < 5);
#pragma unroll
      for (int r = 0; r < 4; ++r) {
        const float e = ok ? __expf(a4[nt][r] - mx4[r]) : 0.f;
        a4[nt][r] = e;
        sm4[r] += e;
      }
    }
    float inv4[4];
#pragma unroll
    for (int r = 0; r < 4; ++r) {
      float ss = sm4[r];
      ss += __shfl_xor(ss, 1);
      ss += __shfl_xor(ss, 2);
      ss += __shfl_xor(ss, 4);
      ss += __shfl_xor(ss, 8);
      inv4[r] = __builtin_amdgcn_rcpf(ss);
    }

    float rwv[4], bdv[4];
#pragma unroll
    for (int r = 0; r < 4; ++r) {
      const int gr = row0w + 4 * q + r;
      rwv[r] = rew[gr];
      bdv[r] = boot[gr] * disc[gr];
    }

#pragma unroll
    for (int nt = 0; nt < 7; ++nt) {
      const int col = nt * 16 + c;
      if ((nt < 6) | (c < 5)) {
        const float qsv = qsup[col];
#pragma unroll
        for (int r = 0; r < 4; ++r) {
          const float p = a4[nt][r] * inv4[r];
          float tz = rwv[r] + bdv[r] * qsv;
          tz = fminf(fmaxf(tz, -10.f), 10.f);
          const float b_ = (tz + 10.f) * 5.f;
          const float fl = floorf(b_), cl = ceilf(b_);
          int li = (int)fl, ui = (int)cl;
          if (ui == li) { if (li > 0) --li; else ++ui; }
          const int rb = (4 * q + r) * 101;
          atomicAdd(&proj[rb + li], p * ((float)ui - b_));
          atomicAdd(&proj[rb + ui], p * (b_ - (float)li));
        }
      }
    }

    {
      const f32x4* p4 = (const f32x4*)proj;
      f32x4* o4 = (f32x4*)(out + (size_t)row0w * 101);
      for (int i = lane; i < 404; i += 64) o4[i] = p4[i];
    }
  }
}

// ================= Fallback: round-4 monolithic (if ws too small) =============
__global__ __launch_bounds__(256, 3)
void sacq_wave(const float* __restrict__ obs,  const float* __restrict__ act,
               const float* __restrict__ rew,  const float* __restrict__ boot,
               const float* __restrict__ disc, const float* __restrict__ qsup,
               const float* __restrict__ b1, const float* __restrict__ g1, const float* __restrict__ be1,
               const float* __restrict__ b2, const float* __restrict__ g2, const float* __restrict__ be2,
               const float* __restrict__ b3, const float* __restrict__ g3, const float* __restrict__ be3,
               const float* __restrict__ b4,
               const __bf16* __restrict__ ws,
               float* __restrict__ out)
{
  __shared__ float sm[13120];
  const int t = threadIdx.x;
  const int wv = t >> 6, lane = t & 63;
  const int q = lane >> 4, c = lane & 15;
  float* smw = sm + wv * 3280;
  __bf16* h1 = (__bf16*)smw;
  __bf16* h2 = (__bf16*)(smw + 2192);
  __bf16* h3 = (__bf16*)smw;
  float*  proj = smw + 576;
  const int row0w = blockIdx.x * 64 + wv * 16;
  const bf16x8* wsf = (const bf16x8*)ws;

  bf16x8 A1[3];
  {
    const float* obsR = obs + (size_t)(row0w + c) * 60;
    const float* actR = act + (size_t)(row0w + c) * 20;
#pragma unroll
    for (int kt = 0; kt < 3; ++kt)
#pragma unroll
      for (int j = 0; j < 8; ++j) {
        const int k = kt * 32 + q * 8 + j;
        float xv = 0.f;
        if (k < 60) xv = obsR[k];
        else if (k < 80) xv = actR[k - 60];
        A1[kt][j] = (__bf16)xv;
      }
  }
  f32x4 acc1[16];
#pragma unroll
  for (int nt = 0; nt < 16; ++nt) {
    const float bb = b1[nt * 16 + c];
    f32x4 vv = {bb, bb, bb, bb};
    acc1[nt] = vv;
  }
#pragma unroll
  for (int kt = 0; kt < 3; ++kt)
#pragma unroll
    for (int nt = 0; nt < 16; ++nt)
      acc1[nt] = __builtin_amdgcn_mfma_f32_16x16x32_bf16(A1[kt], wsf[(kt * 16 + nt) * 64 + lane], acc1[nt], 0, 0, 0);
  {
    float mu[4], rs[4];
#pragma unroll
    for (int r = 0; r < 4; ++r) {
      float s = 0.f, s2 = 0.f;
#pragma unroll
      for (int nt = 0; nt < 16; ++nt) { const float v = acc1[nt][r]; s += v; s2 += v * v; }
      s += __shfl_xor(s, 1); s2 += __shfl_xor(s2, 1);
      s += __shfl_xor(s, 2); s2 += __shfl_xor(s2, 2);
      s += __shfl_xor(s, 4); s2 += __shfl_xor(s2, 4);
      s += __shfl_xor(s, 8); s2 += __shfl_xor(s2, 8);
      const float m = s * (1.f / 256.f);
      mu[r] = m;
      rs[r] = rsqrtf(s2 * (1.f / 256.f) - m * m + 1e-5f);
    }
#pragma unroll
    for (int nt = 0; nt < 16; ++nt) {
      const int col = nt * 16 + c;
      const float gg = g1[col], bb = be1[col];
#pragma unroll
      for (int r = 0; r < 4; ++r) {
        float v = (acc1[nt][r] - mu[r]) * rs[r] * gg + bb;
        v = v * __builtin_amdgcn_rcpf(1.f + __expf(-v));
        h1[(4 * q + r) * 264 + col] = (__bf16)v;
      }
    }
  }
  {
    f32x4 acc2[8];
#pragma unroll
    for (int nt = 0; nt < 8; ++nt) {
      const float bb = b2[nt * 16 + c];
      f32x4 vv = {bb, bb, bb, bb};
      acc2[nt] = vv;
    }
#pragma unroll
    for (int kt = 0; kt < 8; ++kt) {
      const bf16x8 A2 = *(const bf16x8*)(h1 + c * 264 + kt * 32 + q * 8);
#pragma unroll
      for (int nt = 0; nt < 8; ++nt)
        acc2[nt] = __builtin_amdgcn_mfma_f32_16x16x32_bf16(A2, wsf[3072 + (kt * 8 + nt) * 64 + lane], acc2[nt], 0, 0, 0);
    }
    float mu[4], rs[4];
#pragma unroll
    for (int r = 0; r < 4; ++r) {
      float s = 0.f, s2 = 0.f;
#pragma unroll
      for (int nt = 0; nt < 8; ++nt) { const float v = acc2[nt][r]; s += v; s2 += v * v; }
      s += __shfl_xor(s, 1); s2 += __shfl_xor(s2, 1);
      s += __shfl_xor(s, 2); s2 += __shfl_xor(s2, 2);
      s += __shfl_xor(s, 4); s2 += __shfl_xor(s2, 4);
      s += __shfl_xor(s, 8); s2 += __shfl_xor(s2, 8);
      const float m = s * (1.f / 128.f);
      mu[r] = m;
      rs[r] = rsqrtf(s2 * (1.f / 128.f) - m * m + 1e-5f);
    }
#pragma unroll
    for (int nt = 0; nt < 8; ++nt) {
      const int col = nt * 16 + c;
      const float gg = g2[col], bb = be2[col];
#pragma unroll
      for (int r = 0; r < 4; ++r) {
        float v = (acc2[nt][r] - mu[r]) * rs[r] * gg + bb;
        v = v * __builtin_amdgcn_rcpf(1.f + __expf(-v));
        h2[(4 * q + r) * 136 + col] = (__bf16)v;
      }
    }
  }
  {
    f32x4 acc3[4];
#pragma unroll
    for (int nt = 0; nt < 4; ++nt) {
      const float bb = b3[nt * 16 + c];
      f32x4 vv = {bb, bb, bb, bb};
      acc3[nt] = vv;
    }
#pragma unroll
    for (int kt = 0; kt < 4; ++kt) {
      const bf16x8 A3 = *(const bf16x8*)(h2 + c * 136 + kt * 32 + q * 8);
#pragma unroll
      for (int nt = 0; nt < 4; ++nt)
        acc3[nt] = __builtin_amdgcn_mfma_f32_16x16x32_bf16(A3, wsf[7168 + (kt * 4 + nt) * 64 + lane], acc3[nt], 0, 0, 0);
    }
    float mu[4], rs[4];
#pragma unroll
    for (int r = 0; r < 4; ++r) {
      float s = 0.f, s2 = 0.f;
#pragma unroll
      for (int nt = 0; nt < 4; ++nt) { const float v = acc3[nt][r]; s += v; s2 += v * v; }
      s += __shfl_xor(s, 1); s2 += __shfl_xor(s2, 1);
      s += __shfl_xor(s, 2); s2 += __shfl_xor(s2, 2);
      s += __shfl_xor(s, 4); s2 += __shfl_xor(s2, 4);
      s += __shfl_xor(s, 8); s2 += __shfl_xor(s2, 8);
      const float m = s * (1.f / 64.f);
      mu[r] = m;
      rs[r] = rsqrtf(s2 * (1.f / 64.f) - m * m + 1e-5f);
    }
#pragma unroll
    for (int nt = 0; nt < 4; ++nt) {
      const int col = nt * 16 + c;
      const float gg = g3[col], bb = be3[col];
#pragma unroll
      for (int r = 0; r < 4; ++r) {
        float v = (acc3[nt][r] - mu[r]) * rs[r] * gg + bb;
        v = v * __builtin_amdgcn_rcpf(1.f + __expf(-v));
        h3[(4 * q + r) * 72 + col] = (__bf16)v;
      }
    }
  }
  {
    f32x4 a4[7];
#pragma unroll
    for (int nt = 0; nt < 7; ++nt) {
      const int col = nt * 16 + c;
      const float bb = (col < 101) ? b4[col] : 0.f;
      f32x4 vv = {bb, bb, bb, bb};
      a4[nt] = vv;
    }
#pragma unroll
    for (int kt = 0; kt < 2; ++kt) {
      const bf16x8 A4 = *(const bf16x8*)(h3 + c * 72 + kt * 32 + q * 8);
#pragma unroll
      for (int nt = 0; nt < 7; ++nt)
        a4[nt] = __builtin_amdgcn_mfma_f32_16x16x32_bf16(A4, wsf[8192 + (kt * 8 + nt) * 64 + lane], a4[nt], 0, 0, 0);
    }
    {
      f32x4 z = {0.f, 0.f, 0.f, 0.f};
      f32x4* p4 = (f32x4*)proj;
      for (int i = lane; i < 404; i += 64) p4[i] = z;
    }
    float mx4[4] = {-3.4e38f, -3.4e38f, -3.4e38f, -3.4e38f};
#pragma unroll
    for (int nt = 0; nt < 7; ++nt) {
      const bool ok = (nt < 6) | (c < 5);
#pragma unroll
      for (int r = 0; r < 4; ++r)
        if (ok) mx4[r] = fmaxf(mx4[r], a4[nt][r]);
    }
#pragma unroll
    for (int r = 0; r < 4; ++r) {
      mx4[r] = fmaxf(mx4[r], __shfl_xor(mx4[r], 1));
      mx4[r] = fmaxf(mx4[r], __shfl_xor(mx4[r], 2));
      mx4[r] = fmaxf(mx4[r], __shfl_xor(mx4[r], 4));
      mx4[r] = fmaxf(mx4[r], __shfl_xor(mx4[r], 8));
    }
    float sm4[4] = {0.f, 0.f, 0.f, 0.f};
#pragma unroll
    for (int nt = 0; nt < 7; ++nt) {
      const bool ok = (nt < 6) | (c < 5);
#pragma unroll
      for (int r = 0; r < 4; ++r) {
        const float e = ok ? __expf(a4[nt][r] - mx4[r]) : 0.f;
        a4[nt][r] = e;
        sm4[r] += e;
      }
    }
    float inv4[4];
#pragma unroll
    for (int r = 0; r < 4; ++r) {
      float s = sm4[r];
      s += __shfl_xor(s, 1);
      s += __shfl_xor(s, 2);
      s += __shfl_xor(s, 4);
      s += __shfl_xor(s, 8);
      inv4[r] = __builtin_amdgcn_rcpf(s);
    }
    float rwv[4], bdv[4];
#pragma unroll
    for (int r = 0; r < 4; ++r) {
      const int gr = row0w + 4 * q + r;
      rwv[r] = rew[gr];
      bdv[r] = boot[gr] * disc[gr];
    }
#pragma unroll
    for (int nt = 0; nt < 7; ++nt) {
      const int col = nt * 16 + c;
      if ((nt < 6) | (c < 5)) {
        const float qsv = qsup[col];
#pragma unroll
        for (int r = 0; r < 4; ++r) {
          const float p = a4[nt][r] * inv4[r];
          float tz = rwv[r] + bdv[r] * qsv;
          tz = fminf(fmaxf(tz, -10.f), 10.f);
          const float b_ = (tz + 10.f) * 5.f;
          const float fl = floorf(b_), cl = ceilf(b_);
          int li = (int)fl, ui = (int)cl;
          if (ui == li) { if (li > 0) --li; else ++ui; }
          const int rb = (4 * q + r) * 101;
          atomicAdd(&proj[rb + li], p * ((float)ui - b_));
          atomicAdd(&proj[rb + ui], p * (b_ - (float)li));
        }
      }
    }
  }
  {
    const f32x4* p4 = (const f32x4*)proj;
    f32x4* o4 = (f32x4*)(out + (size_t)row0w * 101);
    for (int i = lane; i < 404; i += 64) o4[i] = p4[i];
  }
}

extern "C" void kernel_launch(void* const* d_in, const int* in_sizes, int n_in,
                              void* d_out, int out_size, void* d_ws, size_t ws_size,
                              hipStream_t stream)
{
  const int B = in_sizes[2];  // rewards: B elements
  __bf16* ws = (__bf16*)d_ws;
  const size_t needW  = 147456;
  const size_t needH2 = (size_t)B * 128 * 2;

  conv_weights<<<dim3(36), dim3(256), 0, stream>>>(
      (const float*)d_in[6], (const float*)d_in[10], (const float*)d_in[14],
      (const float*)d_in[18], ws);

  if (ws_size >= needW + needH2) {
    __bf16* h2f = (__bf16*)((char*)d_ws + needW);
    k12<<<dim3(B / 64), dim3(256), 0, stream>>>(
        (const float*)d_in[0], (const float*)d_in[1],
        (const float*)d_in[7], (const float*)d_in[8], (const float*)d_in[9],
        (const float*)d_in[11], (const float*)d_in[12], (const float*)d_in[13],
        ws, h2f);
    k34<<<dim3(B / 128), dim3(256), 0, stream>>>(
        (const float*)d_in[2], (const float*)d_in[3], (const float*)d_in[4],
        (const float*)d_in[5],
        (const float*)d_in[15], (const float*)d_in[16], (const float*)d_in[17],
        (const float*)d_in[19], ws, h2f, (float*)d_out);
  } else {
    sacq_wave<<<dim3(B / 64), dim3(256), 0, stream>>>(
        (const float*)d_in[0],  (const float*)d_in[1],  (const float*)d_in[2],
        (const float*)d_in[3],  (const float*)d_in[4],  (const float*)d_in[5],
        (const float*)d_in[7],  (const float*)d_in[8],  (const float*)d_in[9],
        (const float*)d_in[11], (const float*)d_in[12], (const float*)d_in[13],
        (const float*)d_in[15], (const float*)d_in[16], (const float*)d_in[17],
        (const float*)d_in[19], ws, (float*)d_out);
  }
}

// Round 6
// 336.882 us; speedup vs baseline: 1.0297x; 1.0297x over previous
//
#include <hip/hip_runtime.h>
#include <math.h>

typedef __bf16 bf16x8 __attribute__((ext_vector_type(8)));
typedef float f32x4 __attribute__((ext_vector_type(4)));

// ---------------- weight conversion: fp32 -> bf16 frag-major in d_ws ----------
// Frag (kt,nt) = 32x16 block of B; lane L holds B[kt*32+(L>>4)*8+j][nt*16+(L&15)],
// j=0..7 -> one 16B chunk at frag*1024 + L*16. Frag ids: L1 0..47 (kt*16+nt),
// L2 48..111 (kt*8+nt), L3 112..127 (kt*4+nt), L4 128..143 (kt*8+nt, N pad 128).
__global__ void conv_weights(const float* __restrict__ W1, const float* __restrict__ W2,
                             const float* __restrict__ W3, const float* __restrict__ W4,
                             __bf16* __restrict__ ws)
{
  const int f = blockIdx.x * 4 + (threadIdx.x >> 6);
  const int lane = threadIdx.x & 63;
  int f0, ntot, Ksrc, Nsrc, off;
  const float* W;
  if (f < 48)       { f0 = f;       ntot = 16; Ksrc = 80;  Nsrc = 256; W = W1; off = 0; }
  else if (f < 112) { f0 = f - 48;  ntot = 8;  Ksrc = 256; Nsrc = 128; W = W2; off = 24576; }
  else if (f < 128) { f0 = f - 112; ntot = 4;  Ksrc = 128; Nsrc = 64;  W = W3; off = 57344; }
  else              { f0 = f - 128; ntot = 8;  Ksrc = 64;  Nsrc = 101; W = W4; off = 65536; }
  const int kt = f0 / ntot, nt = f0 % ntot;
  const int q = lane >> 4, c = lane & 15;
  const int n = nt * 16 + c;
  bf16x8 v;
#pragma unroll
  for (int j = 0; j < 8; ++j) {
    const int k = kt * 32 + q * 8 + j;
    const float x = (k < Ksrc && n < Nsrc) ? W[k * Nsrc + n] : 0.f;
    v[j] = (__bf16)x;
  }
  ((bf16x8*)(ws + off))[f0 * 64 + lane] = v;
}

// ---- async-stage one 8-frag (8 KB) chunk: each wave DMAs 2 frags ------------
__device__ __forceinline__ void stage8(const __bf16* __restrict__ ws,
                                       __bf16* __restrict__ buf,
                                       int f0, int wv, int lane)
{
#pragma unroll
  for (int i = 0; i < 2; ++i) {
    const int f = wv * 2 + i;
    __builtin_amdgcn_global_load_lds(
        (const __attribute__((address_space(1))) void*)(ws + (size_t)(f0 + f) * 512 + lane * 8),
        (__attribute__((address_space(3))) void*)(buf + f * 512),
        16, 0, 0);
  }
}

__device__ __forceinline__ bf16x8 wfrag(const __bf16* __restrict__ buf, int slot, int lane)
{
  return *(const bf16x8*)(buf + slot * 512 + lane * 8);
}

// ---------------- fused forward: LDS weight pipeline, wave-owned rows ---------
// Block = 4 waves x 16 rows. Weights flow through a shared 2x8KB double buffer
// via global_load_lds (async DMA, drained by the per-chunk __syncthreads).
// 18 chunks total: L1 6, L2 8, L3 2, L4 2. Activations stay wave-private.
// LDS: 16384 (wbuf) + 4*13120 (acts) = 68864 B -> 2 blocks/CU.

__global__ __launch_bounds__(256, 2)
void sacq_fused(const float* __restrict__ obs,  const float* __restrict__ act,
                const float* __restrict__ rew,  const float* __restrict__ boot,
                const float* __restrict__ disc, const float* __restrict__ qsup,
                const float* __restrict__ b1, const float* __restrict__ g1, const float* __restrict__ be1,
                const float* __restrict__ b2, const float* __restrict__ g2, const float* __restrict__ be2,
                const float* __restrict__ b3, const float* __restrict__ g3, const float* __restrict__ be3,
                const float* __restrict__ b4,
                const __bf16* __restrict__ ws,
                float* __restrict__ out)
{
  __shared__ __bf16 wbufA[4096];
  __shared__ __bf16 wbufB[4096];
  __shared__ float acts[4][3280];
  const int t = threadIdx.x;
  const int wv = t >> 6, lane = t & 63;
  const int q = lane >> 4, c = lane & 15;
  float* smw = &acts[wv][0];
  __bf16* h1 = (__bf16*)smw;             // [16][264]
  __bf16* h2 = (__bf16*)(smw + 2192);    // [16][136]
  __bf16* h3 = (__bf16*)smw;             // [16][72]   (h1 dead)
  float*  proj = smw + 576;              // [16][101]  (h1 dead)
  const int row0w = blockIdx.x * 64 + wv * 16;

  // ---- kick chunk 0 (L1 kt0 nt0-7) into bufA, then build A1 while it flies
  stage8(ws, wbufA, 0, wv, lane);

  bf16x8 A1[3];
  {
    const float4* ob4 = (const float4*)(obs + (size_t)(row0w + c) * 60);
    const float4* ac4 = (const float4*)(act + (size_t)(row0w + c) * 20);
#pragma unroll
    for (int kt = 0; kt < 3; ++kt) {
      const int k0 = kt * 32 + q * 8;
      float v[8];
      if (k0 < 56) {
        const float4 a = ob4[k0 / 4], b = ob4[k0 / 4 + 1];
        v[0]=a.x; v[1]=a.y; v[2]=a.z; v[3]=a.w; v[4]=b.x; v[5]=b.y; v[6]=b.z; v[7]=b.w;
      } else if (k0 == 56) {
        const float4 a = ob4[14], b = ac4[0];
        v[0]=a.x; v[1]=a.y; v[2]=a.z; v[3]=a.w; v[4]=b.x; v[5]=b.y; v[6]=b.z; v[7]=b.w;
      } else if (k0 < 80) {
        const float4 a = ac4[(k0 - 60) / 4], b = ac4[(k0 - 60) / 4 + 1];
        v[0]=a.x; v[1]=a.y; v[2]=a.z; v[3]=a.w; v[4]=b.x; v[5]=b.y; v[6]=b.z; v[7]=b.w;
      } else {
#pragma unroll
        for (int j = 0; j < 8; ++j) v[j] = 0.f;
      }
#pragma unroll
      for (int j = 0; j < 8; ++j) A1[kt][j] = (__bf16)v[j];
    }
  }

  // ---- Layer 1 accumulators (bias init overlaps DMA)
  f32x4 acc1[16];
#pragma unroll
  for (int nt = 0; nt < 16; ++nt) {
    const float bb = b1[nt * 16 + c];
    f32x4 vv = {bb, bb, bb, bb};
    acc1[nt] = vv;
  }
  __syncthreads();   // drains chunk-0 DMA

  // ---- L1: 6 chunks (kt = ci>>1, nt half = ci&1)
#pragma unroll
  for (int ci = 0; ci < 6; ++ci) {
    __bf16* curb = (ci & 1) ? wbufB : wbufA;
    __bf16* nxtb = (ci & 1) ? wbufA : wbufB;
    stage8(ws, nxtb, (ci < 5) ? (ci + 1) * 8 : 48, wv, lane);
    const int kt = ci >> 1, nb = (ci & 1) * 8;
#pragma unroll
    for (int j = 0; j < 8; ++j)
      acc1[nb + j] = __builtin_amdgcn_mfma_f32_16x16x32_bf16(A1[kt], wfrag(curb, j, lane), acc1[nb + j], 0, 0, 0);
    __syncthreads();
  }

  // ---- LN(256)+SiLU -> h1   (L2 kt0 chunk already staged, sits in bufA)
  {
    float mu[4], rs[4];
#pragma unroll
    for (int r = 0; r < 4; ++r) {
      float s = 0.f, s2 = 0.f;
#pragma unroll
      for (int nt = 0; nt < 16; ++nt) { const float v = acc1[nt][r]; s += v; s2 += v * v; }
      s += __shfl_xor(s, 1); s2 += __shfl_xor(s2, 1);
      s += __shfl_xor(s, 2); s2 += __shfl_xor(s2, 2);
      s += __shfl_xor(s, 4); s2 += __shfl_xor(s2, 4);
      s += __shfl_xor(s, 8); s2 += __shfl_xor(s2, 8);
      const float m = s * (1.f / 256.f);
      mu[r] = m;
      rs[r] = rsqrtf(s2 * (1.f / 256.f) - m * m + 1e-5f);
    }
#pragma unroll
    for (int nt = 0; nt < 16; ++nt) {
      const int col = nt * 16 + c;
      const float gg = g1[col], bb = be1[col];
#pragma unroll
      for (int r = 0; r < 4; ++r) {
        float v = (acc1[nt][r] - mu[r]) * rs[r] * gg + bb;
        v = v * __builtin_amdgcn_rcpf(1.f + __expf(-v));
        h1[(4 * q + r) * 264 + col] = (__bf16)v;
      }
    }
  }

  // ---- L2: 8 chunks (one kt each)
  f32x4 acc2[8];
#pragma unroll
  for (int nt = 0; nt < 8; ++nt) {
    const float bb = b2[nt * 16 + c];
    f32x4 vv = {bb, bb, bb, bb};
    acc2[nt] = vv;
  }
#pragma unroll
  for (int kt = 0; kt < 8; ++kt) {
    __bf16* curb = (kt & 1) ? wbufB : wbufA;
    __bf16* nxtb = (kt & 1) ? wbufA : wbufB;
    stage8(ws, nxtb, (kt < 7) ? 48 + (kt + 1) * 8 : 112, wv, lane);
    const bf16x8 A2 = *(const bf16x8*)(h1 + c * 264 + kt * 32 + q * 8);
#pragma unroll
    for (int nt = 0; nt < 8; ++nt)
      acc2[nt] = __builtin_amdgcn_mfma_f32_16x16x32_bf16(A2, wfrag(curb, nt, lane), acc2[nt], 0, 0, 0);
    __syncthreads();
  }

  // ---- LN(128)+SiLU -> h2
  {
    float mu[4], rs[4];
#pragma unroll
    for (int r = 0; r < 4; ++r) {
      float s = 0.f, s2 = 0.f;
#pragma unroll
      for (int nt = 0; nt < 8; ++nt) { const float v = acc2[nt][r]; s += v; s2 += v * v; }
      s += __shfl_xor(s, 1); s2 += __shfl_xor(s2, 1);
      s += __shfl_xor(s, 2); s2 += __shfl_xor(s2, 2);
      s += __shfl_xor(s, 4); s2 += __shfl_xor(s2, 4);
      s += __shfl_xor(s, 8); s2 += __shfl_xor(s2, 8);
      const float m = s * (1.f / 128.f);
      mu[r] = m;
      rs[r] = rsqrtf(s2 * (1.f / 128.f) - m * m + 1e-5f);
    }
#pragma unroll
    for (int nt = 0; nt < 8; ++nt) {
      const int col = nt * 16 + c;
      const float gg = g2[col], bb = be2[col];
#pragma unroll
      for (int r = 0; r < 4; ++r) {
        float v = (acc2[nt][r] - mu[r]) * rs[r] * gg + bb;
        v = v * __builtin_amdgcn_rcpf(1.f + __expf(-v));
        h2[(4 * q + r) * 136 + col] = (__bf16)v;
      }
    }
  }

  // ---- L3: 2 chunks (2 kt x 4 nt each)
  f32x4 acc3[4];
#pragma unroll
  for (int nt = 0; nt < 4; ++nt) {
    const float bb = b3[nt * 16 + c];
    f32x4 vv = {bb, bb, bb, bb};
    acc3[nt] = vv;
  }
#pragma unroll
  for (int cc = 0; cc < 2; ++cc) {
    __bf16* curb = (cc & 1) ? wbufB : wbufA;
    __bf16* nxtb = (cc & 1) ? wbufA : wbufB;
    stage8(ws, nxtb, (cc == 0) ? 120 : 128, wv, lane);
#pragma unroll
    for (int k2 = 0; k2 < 2; ++k2) {
      const int kt = cc * 2 + k2;
      const bf16x8 A3 = *(const bf16x8*)(h2 + c * 136 + kt * 32 + q * 8);
#pragma unroll
      for (int nt = 0; nt < 4; ++nt)
        acc3[nt] = __builtin_amdgcn_mfma_f32_16x16x32_bf16(A3, wfrag(curb, k2 * 4 + nt, lane), acc3[nt], 0, 0, 0);
    }
    __syncthreads();
  }

  // ---- LN(64)+SiLU -> h3 (overlay; h1 dead)
  {
    float mu[4], rs[4];
#pragma unroll
    for (int r = 0; r < 4; ++r) {
      float s = 0.f, s2 = 0.f;
#pragma unroll
      for (int nt = 0; nt < 4; ++nt) { const float v = acc3[nt][r]; s += v; s2 += v * v; }
      s += __shfl_xor(s, 1); s2 += __shfl_xor(s2, 1);
      s += __shfl_xor(s, 2); s2 += __shfl_xor(s2, 2);
      s += __shfl_xor(s, 4); s2 += __shfl_xor(s2, 4);
      s += __shfl_xor(s, 8); s2 += __shfl_xor(s2, 8);
      const float m = s * (1.f / 64.f);
      mu[r] = m;
      rs[r] = rsqrtf(s2 * (1.f / 64.f) - m * m + 1e-5f);
    }
#pragma unroll
    for (int nt = 0; nt < 4; ++nt) {
      const int col = nt * 16 + c;
      const float gg = g3[col], bb = be3[col];
#pragma unroll
      for (int r = 0; r < 4; ++r) {
        float v = (acc3[nt][r] - mu[r]) * rs[r] * gg + bb;
        v = v * __builtin_amdgcn_rcpf(1.f + __expf(-v));
        h3[(4 * q + r) * 72 + col] = (__bf16)v;
      }
    }
  }

  // ---- L4: 2 chunks (kt0 in bufA, kt1 staged into bufB)
  f32x4 a4[7];
#pragma unroll
  for (int nt = 0; nt < 7; ++nt) {
    const int col = nt * 16 + c;
    const float bb = (col < 101) ? b4[col] : 0.f;
    f32x4 vv = {bb, bb, bb, bb};
    a4[nt] = vv;
  }
#pragma unroll
  for (int kt = 0; kt < 2; ++kt) {
    __bf16* curb = kt ? wbufB : wbufA;
    if (kt == 0) stage8(ws, wbufB, 136, wv, lane);
    const bf16x8 A4 = *(const bf16x8*)(h3 + c * 72 + kt * 32 + q * 8);
#pragma unroll
    for (int nt = 0; nt < 7; ++nt)
      a4[nt] = __builtin_amdgcn_mfma_f32_16x16x32_bf16(A4, wfrag(curb, nt, lane), a4[nt], 0, 0, 0);
    __syncthreads();
  }

  // ================= epilogue: softmax + C51 projection (wave-local) =========
  {
    {
      f32x4 z = {0.f, 0.f, 0.f, 0.f};
      f32x4* p4 = (f32x4*)proj;
      for (int i = lane; i < 404; i += 64) p4[i] = z;
    }
    float mx4[4] = {-3.4e38f, -3.4e38f, -3.4e38f, -3.4e38f};
#pragma unroll
    for (int nt = 0; nt < 7; ++nt) {
      const bool ok = (nt < 6) | (c < 5);
#pragma unroll
      for (int r = 0; r < 4; ++r)
        if (ok) mx4[r] = fmaxf(mx4[r], a4[nt][r]);
    }
#pragma unroll
    for (int r = 0; r < 4; ++r) {
      mx4[r] = fmaxf(mx4[r], __shfl_xor(mx4[r], 1));
      mx4[r] = fmaxf(mx4[r], __shfl_xor(mx4[r], 2));
      mx4[r] = fmaxf(mx4[r], __shfl_xor(mx4[r], 4));
      mx4[r] = fmaxf(mx4[r], __shfl_xor(mx4[r], 8));
    }
    float sm4[4] = {0.f, 0.f, 0.f, 0.f};
#pragma unroll
    for (int nt = 0; nt < 7; ++nt) {
      const bool ok = (nt < 6) | (c < 5);
#pragma unroll
      for (int r = 0; r < 4; ++r) {
        const float e = ok ? __expf(a4[nt][r] - mx4[r]) : 0.f;
        a4[nt][r] = e;
        sm4[r] += e;
      }
    }
    float inv4[4];
#pragma unroll
    for (int r = 0; r < 4; ++r) {
      float s = sm4[r];
      s += __shfl_xor(s, 1);
      s += __shfl_xor(s, 2);
      s += __shfl_xor(s, 4);
      s += __shfl_xor(s, 8);
      inv4[r] = __builtin_amdgcn_rcpf(s);
    }
    float rwv[4], bdv[4];
#pragma unroll
    for (int r = 0; r < 4; ++r) {
      const int gr = row0w + 4 * q + r;
      rwv[r] = rew[gr];
      bdv[r] = boot[gr] * disc[gr];
    }
#pragma unroll
    for (int nt = 0; nt < 7; ++nt) {
      const int col = nt * 16 + c;
      if ((nt < 6) | (c < 5)) {
        const float qsv = qsup[col];
#pragma unroll
        for (int r = 0; r < 4; ++r) {
          const float p = a4[nt][r] * inv4[r];
          float tz = rwv[r] + bdv[r] * qsv;
          tz = fminf(fmaxf(tz, -10.f), 10.f);
          const float b_ = (tz + 10.f) * 5.f;
          const float fl = floorf(b_), cl = ceilf(b_);
          int li = (int)fl, ui = (int)cl;
          if (ui == li) { if (li > 0) --li; else ++ui; }
          const int rb = (4 * q + r) * 101;
          atomicAdd(&proj[rb + li], p * ((float)ui - b_));
          atomicAdd(&proj[rb + ui], p * (b_ - (float)li));
        }
      }
    }
  }

  // ---- coalesced float4 writeout of this wave's 16x101 block
  {
    const f32x4* p4 = (const f32x4*)proj;
    f32x4* o4 = (f32x4*)(out + (size_t)row0w * 101);
    for (int i = lane; i < 404; i += 64) o4[i] = p4[i];
  }
}

extern "C" void kernel_launch(void* const* d_in, const int* in_sizes, int n_in,
                              void* d_out, int out_size, void* d_ws, size_t ws_size,
                              hipStream_t stream)
{
  const int B = in_sizes[2];  // rewards: B elements
  __bf16* ws = (__bf16*)d_ws; // 147456 B used

  conv_weights<<<dim3(36), dim3(256), 0, stream>>>(
      (const float*)d_in[6], (const float*)d_in[10], (const float*)d_in[14],
      (const float*)d_in[18], ws);

  sacq_fused<<<dim3(B / 64), dim3(256), 0, stream>>>(
      (const float*)d_in[0],  (const float*)d_in[1],  (const float*)d_in[2],
      (const float*)d_in[3],  (const float*)d_in[4],  (const float*)d_in[5],
      (const float*)d_in[7],  (const float*)d_in[8],  (const float*)d_in[9],
      (const float*)d_in[11], (const float*)d_in[12], (const float*)d_in[13],
      (const float*)d_in[15], (const float*)d_in[16], (const float*)d_in[17],
      (const float*)d_in[19], ws, (float*)d_out);
}